// Round 3
// baseline (4725.750 us; speedup 1.0000x reference)
//
#include <hip/hip_runtime.h>
#include <stdint.h>

// ---------------------------------------------------------------------------
// 3-layer bidirectional LSTM encoder (B=32, T=512, U=256, EMB=300).
// Dtype-agnostic: k_detect probes whether float tensors arrived as float32 or
// bfloat16; ingestion AND the final output writes branch on that flag.
// Internal compute: bf16 MFMA matvecs, fp32 gates/cell state.
//
//  - Embedding gather -> X0 [16384][320] bf16 (K padded 300->320).
//  - Per layer: GEMM XG[t*32+b][2048] = x @ [Wi_f | Wi_b] + bias, then one
//    scan launch runs both directions: 32 WGs x 256 thr; WG (d,r) owns 16
//    h-units of direction d; Wh slice preloaded in VGPRs as MFMA B-frags.
//    Per step: spin on agent-scope counter until all 16 slices of h_s are
//    published, load h_s [32][256] bf16, MFMA matvec, fp32 gates, publish
//    h_{s+1} slice with release atomicAdd (cross-XCD safe).
//  - tin = (d ? s : 511-s) handles Keras go_backwards; out[t] = h_f[t+1] +
//    h_b[512-t]; epilogue emits [out, hf, cf, hb, cb] in the detected dtype.
// ---------------------------------------------------------------------------

typedef unsigned short u16;
typedef __bf16 bf16x8 __attribute__((ext_vector_type(8)));
typedef float f32x4 __attribute__((ext_vector_type(4)));

#define SCOPE_AGENT __HIP_MEMORY_SCOPE_AGENT

__device__ __forceinline__ float bf2f(u16 u) { return __uint_as_float(((unsigned)u) << 16); }
__device__ __forceinline__ u16 f2bf(float f) {
  unsigned u = __float_as_uint(f);
  unsigned r = (u + 0x7FFFu + ((u >> 16) & 1u)) >> 16;
  return (u16)r;
}
__device__ __forceinline__ float rdW(const void* p, size_t i, int isf) {
  return isf ? ((const float*)p)[i] : bf2f(((const u16*)p)[i]);
}
__device__ __forceinline__ float sigf(float x) { return 1.f / (1.f + __expf(-x)); }
__device__ __forceinline__ float tanh_(float x) { float e = __expf(2.f * x); return 1.f - 2.f / (e + 1.f); }

// ---- ws layout (bytes), total 118,067,328 ----
#define O_X0   0ull            // u16 [16384][320]; reused as A23 u16[16384][256]
#define O_WC1  10485760ull     // u16 [2048][320]  (Wi1 B^T, K padded)
#define O_WC2  11796480ull     // u16 [2048][256]
#define O_WC3  12845056ull     // u16 [2048][256]
#define O_WH   13893632ull     // u16 [6][256][1024] canonical bf16 Wh
#define O_BIAS 17039360ull     // float [3][2048]
#define O_FLAG 17063936ull     // uint: 1 = float32 tensors, 0 = bf16
#define O_CNT  17064000ull     // uint [3][2][513]
#define O_C0   17076352ull     // float [2][32][256] zeros
#define O_CA   17141888ull
#define O_CB   17207424ull
#define O_CC   17272960ull
#define O_HSA  17338496ull     // u16 [2][513][32][256]
#define O_HSB  34148480ull     // u16 [2][513][32][256]
#define O_XG   50958464ull     // u16 [16384][2048]

// ---------------------------------------------------------------------------
// Dtype probe: emb ~ N(0, 0.05). bf16-packed => low u16 of each 32b word has
// exponent field ((w>>7)&0xFF) in [100,128) essentially always. float32 =>
// those bits are interior mantissa bits (~uniform) -> ~11% hit rate.
__global__ void k_detect(const unsigned* __restrict__ embw, unsigned* flag) {
  int tid = threadIdx.x;
  unsigned w = embw[tid];
  unsigned e = (w >> 7) & 0xFFu;
  unsigned long long m = __ballot(e >= 100u && e < 128u);
  if (tid == 0) flag[0] = (__popcll(m) >= 32) ? 0u : 1u;
}

// ---------------------------------------------------------------------------
__global__ __launch_bounds__(256) void k_prep(
    const void* Wi1f, const void* Wi1b, const void* Wi2f, const void* Wi2b,
    const void* Wi3f, const void* Wi3b,
    const void* Wh1f, const void* Wh1b, const void* Wh2f, const void* Wh2b,
    const void* Wh3f, const void* Wh3b,
    const void* b1f, const void* b1b, const void* b2f, const void* b2b,
    const void* b3f, const void* b3b,
    const unsigned* __restrict__ flag,
    u16* Wc1, u16* Wc2, u16* Wc3, u16* WhC, float* bias, unsigned* cnt, float* c0) {
  const int isf = (int)flag[0];
  int idx = blockIdx.x * 256 + threadIdx.x;
  if (idx < 2048 * 320) {  // Wc1[n][k] (B^T), zero-pad k>=300
    int n = idx / 320, k = idx - n * 320;
    int dd = n >> 10, col = n & 1023;
    const void* W = dd ? Wi1b : Wi1f;
    Wc1[idx] = (k < 300) ? f2bf(rdW(W, (size_t)k * 1024 + col, isf)) : (u16)0;
  }
  if (idx < 2048 * 256) {
    int n = idx >> 8, k = idx & 255;
    int dd = n >> 10, col = n & 1023;
    Wc2[idx] = f2bf(rdW(dd ? Wi2b : Wi2f, (size_t)k * 1024 + col, isf));
    Wc3[idx] = f2bf(rdW(dd ? Wi3b : Wi3f, (size_t)k * 1024 + col, isf));
  }
  if (idx < 3 * 2048) {
    int l = idx >> 11, n = idx & 2047;
    int dd = n >> 10, col = n & 1023;
    const void* bp = (l == 0) ? (dd ? b1b : b1f) : (l == 1) ? (dd ? b2b : b2f) : (dd ? b3b : b3f);
    bias[idx] = rdW(bp, col, isf);
  }
  if (idx < 3 * 2 * 513) cnt[idx] = 0u;
  if (idx < 2 * 32 * 256) c0[idx] = 0.f;
  if (idx < 6 * 262144) {  // canonical bf16 Wh copies
    int mat = idx >> 18, pos = idx & 262143;
    const void* W = (mat == 0) ? Wh1f : (mat == 1) ? Wh1b : (mat == 2) ? Wh2f
                   : (mat == 3) ? Wh2b : (mat == 4) ? Wh3f : Wh3b;
    WhC[idx] = f2bf(rdW(W, (size_t)pos, isf));
  }
}

// ---------------------------------------------------------------------------
__global__ __launch_bounds__(256) void k_embed(const int* __restrict__ x,
                                               const void* __restrict__ emb,
                                               const unsigned* __restrict__ flag,
                                               u16* __restrict__ X0) {
  const int isf = (int)flag[0];
  int row = blockIdx.x;              // row = t*32 + b
  int t = row >> 5, b = row & 31;
  int tok = x[b * 512 + t];
  int tid = threadIdx.x;
  if (tid < 150) {
    unsigned pk;
    if (isf) {
      float2 v = *(const float2*)((const float*)emb + (size_t)tok * 300 + tid * 2);
      pk = (unsigned)f2bf(v.x) | ((unsigned)f2bf(v.y) << 16);
    } else {
      pk = *(const unsigned*)((const u16*)emb + (size_t)tok * 300 + tid * 2);
    }
    *(unsigned*)(X0 + (size_t)row * 320 + tid * 2) = pk;
  } else if (tid < 160) {
    *(unsigned*)(X0 + (size_t)row * 320 + 300 + (tid - 150) * 2) = 0u;
  }
}

// ---------------------------------------------------------------------------
// XG[m][n] = A[m][:] . Bt[n][:] + bias[n], M=16384, N=2048, K in {256,320}.
__global__ __launch_bounds__(256) void k_gemm(const u16* __restrict__ A,
                                              const u16* __restrict__ Bt,
                                              const float* __restrict__ bias,
                                              u16* __restrict__ XG, int K) {
  __shared__ u16 As[128 * 32];
  __shared__ u16 Bs[128 * 32];
  const int tid = threadIdx.x;
  const int wv = tid >> 6, L = tid & 63, quad = L >> 4, l15 = L & 15;
  const int wm = wv & 1, wn = wv >> 1;
  const int bm = blockIdx.x & 127, bn = blockIdx.x >> 7;
  const u16* Ab = A + (size_t)(bm * 128) * K;
  const u16* Bb = Bt + (size_t)(bn * 128) * K;
  f32x4 z = {0.f, 0.f, 0.f, 0.f};
  f32x4 acc[4][4];
#pragma unroll
  for (int a = 0; a < 4; ++a)
#pragma unroll
    for (int b2 = 0; b2 < 4; ++b2) acc[a][b2] = z;
  const int srow = tid >> 2, sk = (tid & 3) * 8;
  for (int k0 = 0; k0 < K; k0 += 32) {
    __syncthreads();
    uint4 a0 = *(const uint4*)(Ab + (size_t)srow * K + k0 + sk);
    uint4 a1 = *(const uint4*)(Ab + (size_t)(srow + 64) * K + k0 + sk);
    uint4 b0 = *(const uint4*)(Bb + (size_t)srow * K + k0 + sk);
    uint4 b1 = *(const uint4*)(Bb + (size_t)(srow + 64) * K + k0 + sk);
    *(uint4*)&As[srow * 32 + sk] = a0;
    *(uint4*)&As[(srow + 64) * 32 + sk] = a1;
    *(uint4*)&Bs[srow * 32 + sk] = b0;
    *(uint4*)&Bs[(srow + 64) * 32 + sk] = b1;
    __syncthreads();
    bf16x8 af[4], bf[4];
#pragma unroll
    for (int t4 = 0; t4 < 4; ++t4) {
      af[t4] = *(const bf16x8*)&As[(wm * 64 + t4 * 16 + l15) * 32 + quad * 8];
      bf[t4] = *(const bf16x8*)&Bs[(wn * 64 + t4 * 16 + l15) * 32 + quad * 8];
    }
#pragma unroll
    for (int mt4 = 0; mt4 < 4; ++mt4)
#pragma unroll
      for (int nt4 = 0; nt4 < 4; ++nt4)
        acc[mt4][nt4] = __builtin_amdgcn_mfma_f32_16x16x32_bf16(af[mt4], bf[nt4], acc[mt4][nt4], 0, 0, 0);
  }
#pragma unroll
  for (int mt4 = 0; mt4 < 4; ++mt4)
#pragma unroll
    for (int nt4 = 0; nt4 < 4; ++nt4)
#pragma unroll
      for (int i = 0; i < 4; ++i) {
        int m = bm * 128 + wm * 64 + mt4 * 16 + quad * 4 + i;
        int n = bn * 128 + wn * 64 + nt4 * 16 + l15;
        XG[(size_t)m * 2048 + n] = f2bf(acc[mt4][nt4][i] + bias[n]);
      }
}

// ---------------------------------------------------------------------------
// Recurrent scan: 32 WGs (d = wg>>4 direction, r = wg&15 unit-slice).
__global__ __launch_bounds__(256) void k_scan(const u16* __restrict__ XG,
                                              const u16* __restrict__ Whf,
                                              const u16* __restrict__ Whb,
                                              u16* hs, const u16* h0src,
                                              const float* __restrict__ c_src,
                                              float* __restrict__ c_dst,
                                              unsigned* cnt) {
  const int wg = blockIdx.x;
  const int d = wg >> 4, r = wg & 15;
  const int tid = threadIdx.x;
  const int wv = tid >> 6, L = tid & 63, quad = L >> 4, l15 = L & 15;
  const int mt = wv & 1, n0 = (wv >> 1) * 2;

  __shared__ u16 Ah[32][264];
  __shared__ float gbuf[32][68];

  const u16* Wh = d ? Whb : Whf;

  // --- preload B fragments (Wh slice): n = l15, k = quad*8+j ---
  union U8 { u16 s[8]; bf16x8 v; };
  U8 bfrag[2][8];
#pragma unroll
  for (int nt2 = 0; nt2 < 2; ++nt2) {
    int gcol = (n0 + nt2) * 256 + r * 16 + l15;
#pragma unroll
    for (int kt = 0; kt < 8; ++kt)
#pragma unroll
      for (int j = 0; j < 8; ++j)
        bfrag[nt2][kt].s[j] = Wh[(size_t)(kt * 32 + quad * 8 + j) * 1024 + gcol];
  }

  // --- persistent cell state: thread owns (b_c, uu0) and (b_c, uu0+8) ---
  const int b_c = tid >> 3, uu0 = tid & 7;
  float cv0 = c_src[(d * 32 + b_c) * 256 + r * 16 + uu0];
  float cv1 = c_src[(d * 32 + b_c) * 256 + r * 16 + uu0 + 8];

  // --- publish h0 slice ---
  {
    u16 v0 = 0, v1 = 0;
    if (h0src) {
      v0 = h0src[(size_t)(d * 513 + 512) * 8192 + b_c * 256 + r * 16 + uu0];
      v1 = h0src[(size_t)(d * 513 + 512) * 8192 + b_c * 256 + r * 16 + uu0 + 8];
    }
    hs[(size_t)(d * 513) * 8192 + b_c * 256 + r * 16 + uu0] = v0;
    hs[(size_t)(d * 513) * 8192 + b_c * 256 + r * 16 + uu0 + 8] = v1;
  }
  __syncthreads();
  if (tid == 0) __hip_atomic_fetch_add(&cnt[d * 513], 1u, __ATOMIC_RELEASE, SCOPE_AGENT);

  for (int s = 0; s < 512; ++s) {
    const int tin = d ? s : 511 - s;

    // prefetch xg (independent of h_s) before the spin
    u16 xgr[2][4];
#pragma unroll
    for (int nt2 = 0; nt2 < 2; ++nt2) {
      int gcol = (n0 + nt2) * 256 + r * 16 + l15;
      const u16* xp = XG + (size_t)(tin * 32 + mt * 16 + quad * 4) * 2048 + d * 1024 + gcol;
#pragma unroll
      for (int i = 0; i < 4; ++i) xgr[nt2][i] = xp[(size_t)i * 2048];
    }

    // wait until all 16 slices of h_s are published
    if (tid == 0) {
      while (__hip_atomic_load(&cnt[d * 513 + s], __ATOMIC_ACQUIRE, SCOPE_AGENT) < 16u) {}
    }
    __syncthreads();

    // load h_s [32][256] bf16 -> LDS
    {
      const u16* hp = hs + (size_t)(d * 513 + s) * 8192;
#pragma unroll
      for (int rep = 0; rep < 4; ++rep) {
        int pos = rep * 2048 + tid * 8;
        uint4 v = *(const uint4*)(hp + pos);
        *(uint4*)&Ah[pos >> 8][pos & 255] = v;
      }
    }
    __syncthreads();

    // matvec: g = h_s @ Wh_slice
    f32x4 acc0 = {0.f, 0.f, 0.f, 0.f}, acc1 = {0.f, 0.f, 0.f, 0.f};
#pragma unroll
    for (int kt = 0; kt < 8; ++kt) {
      bf16x8 ah = *(const bf16x8*)&Ah[mt * 16 + l15][kt * 32 + quad * 8];
      acc0 = __builtin_amdgcn_mfma_f32_16x16x32_bf16(ah, bfrag[0][kt].v, acc0, 0, 0, 0);
      acc1 = __builtin_amdgcn_mfma_f32_16x16x32_bf16(ah, bfrag[1][kt].v, acc1, 0, 0, 0);
    }

    // gate pre-activations -> LDS (cross-wave exchange)
#pragma unroll
    for (int i = 0; i < 4; ++i) {
      int bb = mt * 16 + quad * 4 + i;
      gbuf[bb][(n0 + 0) * 16 + l15] = acc0[i] + bf2f(xgr[0][i]);
      gbuf[bb][(n0 + 1) * 16 + l15] = acc1[i] + bf2f(xgr[1][i]);
    }
    __syncthreads();

    // gates (Keras order i,f,c,o), update c, emit h slice
#pragma unroll
    for (int p = 0; p < 2; ++p) {
      int uu = uu0 + p * 8;
      float gi = gbuf[b_c][uu];
      float gf = gbuf[b_c][16 + uu];
      float gg = gbuf[b_c][32 + uu];
      float go = gbuf[b_c][48 + uu];
      float& c = p ? cv1 : cv0;
      c = sigf(gf) * c + sigf(gi) * tanh_(gg);
      float h = sigf(go) * tanh_(c);
      hs[(size_t)(d * 513 + s + 1) * 8192 + b_c * 256 + r * 16 + uu] = f2bf(h);
      if (s == 511) c_dst[(d * 32 + b_c) * 256 + r * 16 + uu] = c;
    }
    __syncthreads();  // drains vmcnt for all waves before the release below
    if (tid == 0) __hip_atomic_fetch_add(&cnt[d * 513 + s + 1], 1u, __ATOMIC_RELEASE, SCOPE_AGENT);
  }
}

// ---------------------------------------------------------------------------
// Next-layer GEMM input: A[t*32+b][u] = bf16( h_f[t+1] + h_b[512-t] )
__global__ __launch_bounds__(256) void k_mkA(const u16* __restrict__ hs, u16* __restrict__ A23) {
  int row = blockIdx.x;
  int t = row >> 5, b = row & 31, u = threadIdx.x;
  float vf = bf2f(hs[(size_t)(t + 1) * 8192 + b * 256 + u]);
  float vb = bf2f(hs[(size_t)(513 + 512 - t) * 8192 + b * 256 + u]);
  A23[(size_t)row * 256 + u] = f2bf(vf + vb);
}

// ---------------------------------------------------------------------------
// Epilogue: writes output in the DETECTED dtype (float32 if flag, else bf16).
__global__ __launch_bounds__(256) void k_epi(const u16* __restrict__ hs,
                                             const float* __restrict__ cC,
                                             const unsigned* __restrict__ flag,
                                             void* __restrict__ outv) {
  const int isf = (int)flag[0];
  float* outf = (float*)outv;
  u16* outb = (u16*)outv;
  int u = threadIdx.x;
  if (blockIdx.x < 16384) {  // out[b][s][u], blockIdx = b*512 + s
    int b = blockIdx.x >> 9, s = blockIdx.x & 511;
    float v = bf2f(hs[(size_t)(s + 1) * 8192 + b * 256 + u]) +
              bf2f(hs[(size_t)(513 + 512 - s) * 8192 + b * 256 + u]);
    size_t o = (size_t)blockIdx.x * 256 + u;
    if (isf) outf[o] = v; else outb[o] = f2bf(v);
  } else {  // final states: hf, cf, hb, cb
    int j = blockIdx.x - 16384;
    const size_t base = 16384ull * 256;
    float vhf = bf2f(hs[(size_t)512 * 8192 + j * 256 + u]);
    float vcf = cC[j * 256 + u];
    float vhb = bf2f(hs[(size_t)1025 * 8192 + j * 256 + u]);
    float vcb = cC[(32 + j) * 256 + u];
    size_t o0 = base + (size_t)j * 256 + u;
    if (isf) {
      outf[o0] = vhf; outf[o0 + 8192] = vcf; outf[o0 + 16384] = vhb; outf[o0 + 24576] = vcb;
    } else {
      outb[o0] = f2bf(vhf); outb[o0 + 8192] = f2bf(vcf);
      outb[o0 + 16384] = f2bf(vhb); outb[o0 + 24576] = f2bf(vcb);
    }
  }
}

// ---------------------------------------------------------------------------
extern "C" void kernel_launch(void* const* d_in, const int* in_sizes, int n_in,
                              void* d_out, int out_size, void* d_ws, size_t ws_size,
                              hipStream_t stream) {
  (void)in_sizes; (void)n_in; (void)out_size; (void)ws_size;
  const int* x   = (const int*)d_in[0];
  const void* emb = d_in[1];
  const void* Wi1f = d_in[2];  const void* Wh1f = d_in[3];  const void* b1f = d_in[4];
  const void* Wi1b = d_in[5];  const void* Wh1b = d_in[6];  const void* b1b = d_in[7];
  const void* Wi2f = d_in[8];  const void* Wh2f = d_in[9];  const void* b2f = d_in[10];
  const void* Wi2b = d_in[11]; const void* Wh2b = d_in[12]; const void* b2b = d_in[13];
  const void* Wi3f = d_in[14]; const void* Wh3f = d_in[15]; const void* b3f = d_in[16];
  const void* Wi3b = d_in[17]; const void* Wh3b = d_in[18]; const void* b3b = d_in[19];

  char* ws = (char*)d_ws;
  u16* X0   = (u16*)(ws + O_X0);
  u16* A23  = (u16*)(ws + O_X0);   // reuse: X0 dead after layer-1 GEMM
  u16* Wc1  = (u16*)(ws + O_WC1);
  u16* Wc2  = (u16*)(ws + O_WC2);
  u16* Wc3  = (u16*)(ws + O_WC3);
  u16* WhC  = (u16*)(ws + O_WH);
  float* bias = (float*)(ws + O_BIAS);
  unsigned* flag = (unsigned*)(ws + O_FLAG);
  unsigned* cnt = (unsigned*)(ws + O_CNT);
  float* c0 = (float*)(ws + O_C0);
  float* cA = (float*)(ws + O_CA);
  float* cB = (float*)(ws + O_CB);
  float* cC = (float*)(ws + O_CC);
  u16* hsA = (u16*)(ws + O_HSA);
  u16* hsB = (u16*)(ws + O_HSB);
  u16* XG  = (u16*)(ws + O_XG);

  k_detect<<<1, 64, 0, stream>>>((const unsigned*)emb, flag);
  k_prep<<<6144, 256, 0, stream>>>(Wi1f, Wi1b, Wi2f, Wi2b, Wi3f, Wi3b,
                                   Wh1f, Wh1b, Wh2f, Wh2b, Wh3f, Wh3b,
                                   b1f, b1b, b2f, b2b, b3f, b3b,
                                   flag, Wc1, Wc2, Wc3, WhC, bias, cnt, c0);
  k_embed<<<16384, 256, 0, stream>>>(x, emb, flag, X0);

  // layer 1
  k_gemm<<<2048, 256, 0, stream>>>(X0, Wc1, bias + 0, XG, 320);
  k_scan<<<32, 256, 0, stream>>>(XG, WhC + 0 * 262144, WhC + 1 * 262144, hsA, nullptr, c0, cA, cnt);
  // layer 2
  k_mkA<<<16384, 256, 0, stream>>>(hsA, A23);
  k_gemm<<<2048, 256, 0, stream>>>(A23, Wc2, bias + 2048, XG, 256);
  k_scan<<<32, 256, 0, stream>>>(XG, WhC + 2 * 262144, WhC + 3 * 262144, hsB, hsA, cA, cB, cnt + 1026);
  // layer 3
  k_mkA<<<16384, 256, 0, stream>>>(hsB, A23);
  k_gemm<<<2048, 256, 0, stream>>>(A23, Wc3, bias + 4096, XG, 256);
  k_scan<<<32, 256, 0, stream>>>(XG, WhC + 4 * 262144, WhC + 5 * 262144, hsA, hsB, cB, cC, cnt + 2052);

  k_epi<<<16416, 256, 0, stream>>>(hsA, cC, flag, d_out);
}

// Round 4
// 4014.106 us; speedup vs baseline: 1.1773x; 1.1773x over previous
//
#include <hip/hip_runtime.h>
#include <stdint.h>

// ---------------------------------------------------------------------------
// 3-layer bidirectional LSTM encoder (B=32, T=512, U=256, EMB=300).
// Scan uses a fence-free cross-WG protocol: h values are published as packed
// dwords via RELAXED agent-scope atomic stores (sc1 -> coherence point), and
// readers poll the data words directly (relaxed agent atomic loads) until
// nonzero. Encoding (XOR 0x80008000 with -0 clamp) guarantees published
// words are nonzero; slots are pre-zeroed. No acquire/release fences =>
// no whole-L2 buffer_inv / buffer_wbl2 per step (round-3 bottleneck).
// ---------------------------------------------------------------------------

typedef unsigned short u16;
typedef __bf16 bf16x8 __attribute__((ext_vector_type(8)));
typedef float f32x4 __attribute__((ext_vector_type(4)));

#define SCOPE_AGENT __HIP_MEMORY_SCOPE_AGENT

__device__ __forceinline__ float bf2f(u16 u) { return __uint_as_float(((unsigned)u) << 16); }
__device__ __forceinline__ u16 f2bf(float f) {
  unsigned u = __float_as_uint(f);
  unsigned r = (u + 0x7FFFu + ((u >> 16) & 1u)) >> 16;
  return (u16)r;
}
__device__ __forceinline__ float rdW(const void* p, size_t i, int isf) {
  return isf ? ((const float*)p)[i] : bf2f(((const u16*)p)[i]);
}
__device__ __forceinline__ float sigf(float x) { return 1.f / (1.f + __expf(-x)); }
__device__ __forceinline__ float tanh_(float x) { float e = __expf(2.f * x); return 1.f - 2.f / (e + 1.f); }

// ---- ws layout (bytes) ----
#define O_X0   0ull            // u16 [16384][320]; reused as A23 u16[16384][256]
#define O_WC1  10485760ull     // u16 [2048][320]  (Wi1 B^T, K padded)
#define O_WC2  11796480ull     // u16 [2048][256]
#define O_WC3  12845056ull     // u16 [2048][256]
#define O_WH   13893632ull     // u16 [6][256][1024] canonical bf16 Wh
#define O_BIAS 17039360ull     // float [3][2048]
#define O_FLAG 17063936ull     // uint: 1 = float32 tensors, 0 = bf16
#define O_C0   17076352ull     // float [2][32][256] zeros
#define O_CA   17141888ull
#define O_CB   17207424ull
#define O_CC   17272960ull
#define O_HSA  17338496ull     // u16 [2][513][32][256] (encoded)
#define O_HSB  34148480ull     // u16 [2][513][32][256] (encoded)
#define O_XG   50958464ull     // u16 [16384][2048]

#define HS_U16 16809984ull     // bytes of one hs buffer
#define HS_U4  1050624         // uint4 count of one hs buffer

// ---------------------------------------------------------------------------
__global__ void k_detect(const unsigned* __restrict__ embw, unsigned* flag) {
  int tid = threadIdx.x;
  unsigned w = embw[tid];
  unsigned e = (w >> 7) & 0xFFu;
  unsigned long long m = __ballot(e >= 100u && e < 128u);
  if (tid == 0) flag[0] = (__popcll(m) >= 32) ? 0u : 1u;
}

// ---------------------------------------------------------------------------
__global__ __launch_bounds__(256) void k_zero(uint4* __restrict__ p, int n) {
  uint4 z = {0u, 0u, 0u, 0u};
  for (int i = blockIdx.x * 256 + threadIdx.x; i < n; i += gridDim.x * 256) p[i] = z;
}

// ---------------------------------------------------------------------------
__global__ __launch_bounds__(256) void k_prep(
    const void* Wi1f, const void* Wi1b, const void* Wi2f, const void* Wi2b,
    const void* Wi3f, const void* Wi3b,
    const void* Wh1f, const void* Wh1b, const void* Wh2f, const void* Wh2b,
    const void* Wh3f, const void* Wh3b,
    const void* b1f, const void* b1b, const void* b2f, const void* b2b,
    const void* b3f, const void* b3b,
    const unsigned* __restrict__ flag,
    u16* Wc1, u16* Wc2, u16* Wc3, u16* WhC, float* bias, float* c0) {
  const int isf = (int)flag[0];
  int idx = blockIdx.x * 256 + threadIdx.x;
  if (idx < 2048 * 320) {  // Wc1[n][k] (B^T), zero-pad k>=300
    int n = idx / 320, k = idx - n * 320;
    int dd = n >> 10, col = n & 1023;
    const void* W = dd ? Wi1b : Wi1f;
    Wc1[idx] = (k < 300) ? f2bf(rdW(W, (size_t)k * 1024 + col, isf)) : (u16)0;
  }
  if (idx < 2048 * 256) {
    int n = idx >> 8, k = idx & 255;
    int dd = n >> 10, col = n & 1023;
    Wc2[idx] = f2bf(rdW(dd ? Wi2b : Wi2f, (size_t)k * 1024 + col, isf));
    Wc3[idx] = f2bf(rdW(dd ? Wi3b : Wi3f, (size_t)k * 1024 + col, isf));
  }
  if (idx < 3 * 2048) {
    int l = idx >> 11, n = idx & 2047;
    int dd = n >> 10, col = n & 1023;
    const void* bp = (l == 0) ? (dd ? b1b : b1f) : (l == 1) ? (dd ? b2b : b2f) : (dd ? b3b : b3f);
    bias[idx] = rdW(bp, col, isf);
  }
  if (idx < 2 * 32 * 256) c0[idx] = 0.f;
  if (idx < 6 * 262144) {  // canonical bf16 Wh copies
    int mat = idx >> 18, pos = idx & 262143;
    const void* W = (mat == 0) ? Wh1f : (mat == 1) ? Wh1b : (mat == 2) ? Wh2f
                   : (mat == 3) ? Wh2b : (mat == 4) ? Wh3f : Wh3b;
    WhC[idx] = f2bf(rdW(W, (size_t)pos, isf));
  }
}

// ---------------------------------------------------------------------------
__global__ __launch_bounds__(256) void k_embed(const int* __restrict__ x,
                                               const void* __restrict__ emb,
                                               const unsigned* __restrict__ flag,
                                               u16* __restrict__ X0) {
  const int isf = (int)flag[0];
  int row = blockIdx.x;              // row = t*32 + b
  int t = row >> 5, b = row & 31;
  int tok = x[b * 512 + t];
  int tid = threadIdx.x;
  if (tid < 150) {
    unsigned pk;
    if (isf) {
      float2 v = *(const float2*)((const float*)emb + (size_t)tok * 300 + tid * 2);
      pk = (unsigned)f2bf(v.x) | ((unsigned)f2bf(v.y) << 16);
    } else {
      pk = *(const unsigned*)((const u16*)emb + (size_t)tok * 300 + tid * 2);
    }
    *(unsigned*)(X0 + (size_t)row * 320 + tid * 2) = pk;
  } else if (tid < 160) {
    *(unsigned*)(X0 + (size_t)row * 320 + 300 + (tid - 150) * 2) = 0u;
  }
}

// ---------------------------------------------------------------------------
// XG[m][n] = A[m][:] . Bt[n][:] + bias[n], M=16384, N=2048, K in {256,320}.
__global__ __launch_bounds__(256) void k_gemm(const u16* __restrict__ A,
                                              const u16* __restrict__ Bt,
                                              const float* __restrict__ bias,
                                              u16* __restrict__ XG, int K) {
  __shared__ u16 As[128 * 32];
  __shared__ u16 Bs[128 * 32];
  const int tid = threadIdx.x;
  const int wv = tid >> 6, L = tid & 63, quad = L >> 4, l15 = L & 15;
  const int wm = wv & 1, wn = wv >> 1;
  const int bm = blockIdx.x & 127, bn = blockIdx.x >> 7;
  const u16* Ab = A + (size_t)(bm * 128) * K;
  const u16* Bb = Bt + (size_t)(bn * 128) * K;
  f32x4 z = {0.f, 0.f, 0.f, 0.f};
  f32x4 acc[4][4];
#pragma unroll
  for (int a = 0; a < 4; ++a)
#pragma unroll
    for (int b2 = 0; b2 < 4; ++b2) acc[a][b2] = z;
  const int srow = tid >> 2, sk = (tid & 3) * 8;
  for (int k0 = 0; k0 < K; k0 += 32) {
    __syncthreads();
    uint4 a0 = *(const uint4*)(Ab + (size_t)srow * K + k0 + sk);
    uint4 a1 = *(const uint4*)(Ab + (size_t)(srow + 64) * K + k0 + sk);
    uint4 b0 = *(const uint4*)(Bb + (size_t)srow * K + k0 + sk);
    uint4 b1 = *(const uint4*)(Bb + (size_t)(srow + 64) * K + k0 + sk);
    *(uint4*)&As[srow * 32 + sk] = a0;
    *(uint4*)&As[(srow + 64) * 32 + sk] = a1;
    *(uint4*)&Bs[srow * 32 + sk] = b0;
    *(uint4*)&Bs[(srow + 64) * 32 + sk] = b1;
    __syncthreads();
    bf16x8 af[4], bf[4];
#pragma unroll
    for (int t4 = 0; t4 < 4; ++t4) {
      af[t4] = *(const bf16x8*)&As[(wm * 64 + t4 * 16 + l15) * 32 + quad * 8];
      bf[t4] = *(const bf16x8*)&Bs[(wn * 64 + t4 * 16 + l15) * 32 + quad * 8];
    }
#pragma unroll
    for (int mt4 = 0; mt4 < 4; ++mt4)
#pragma unroll
      for (int nt4 = 0; nt4 < 4; ++nt4)
        acc[mt4][nt4] = __builtin_amdgcn_mfma_f32_16x16x32_bf16(af[mt4], bf[nt4], acc[mt4][nt4], 0, 0, 0);
  }
#pragma unroll
  for (int mt4 = 0; mt4 < 4; ++mt4)
#pragma unroll
    for (int nt4 = 0; nt4 < 4; ++nt4)
#pragma unroll
      for (int i = 0; i < 4; ++i) {
        int m = bm * 128 + wm * 64 + mt4 * 16 + quad * 4 + i;
        int n = bn * 128 + wn * 64 + nt4 * 16 + l15;
        XG[(size_t)m * 2048 + n] = f2bf(acc[mt4][nt4][i] + bias[n]);
      }
}

// ---------------------------------------------------------------------------
// Recurrent scan: 16 WGs x 512 thr. d = wg>>3 direction, r = wg&7 unit-slice
// (32 units each). hs holds ENCODED bf16 pairs (XOR 0x80008000, nonzero).
__global__ __launch_bounds__(512) void k_scan(const u16* __restrict__ XG,
                                              const u16* __restrict__ Whf,
                                              const u16* __restrict__ Whb,
                                              u16* hs, const u16* h0src,
                                              const float* __restrict__ c_src,
                                              float* __restrict__ c_dst) {
  const int wg = blockIdx.x;
  const int d = wg >> 3, r = wg & 7;
  const int tid = threadIdx.x;
  const int wv = tid >> 6, L = tid & 63, quad = L >> 4, l15 = L & 15;
  const int mt = wv & 1, p = wv >> 1;   // p in 0..3 -> n-tiles 2p, 2p+1

  __shared__ u16 Ah[32][264];
  __shared__ float gbuf[32][132];

  const u16* Wh = d ? Whb : Whf;

  // --- preload B fragments: tile nt = 2p+t -> col (nt>>1)*256 + r*32 + (nt&1)*16 + l15
  union U8 { u16 s[8]; bf16x8 v; };
  U8 bfrag[2][8];
#pragma unroll
  for (int t = 0; t < 2; ++t) {
    int nt = 2 * p + t;
    int col = (nt >> 1) * 256 + r * 32 + (nt & 1) * 16 + l15;
#pragma unroll
    for (int kt = 0; kt < 8; ++kt)
#pragma unroll
      for (int j = 0; j < 8; ++j)
        bfrag[t][kt].s[j] = Wh[(size_t)(kt * 32 + quad * 8 + j) * 1024 + col];
  }

  // --- cell state: thread (b_c, j16) owns units gu, gu+1 ---
  const int b_c = tid >> 4, j16 = tid & 15;
  const int gu = r * 32 + 2 * j16;
  float cv0 = c_src[(d * 32 + b_c) * 256 + gu];
  float cv1 = c_src[(d * 32 + b_c) * 256 + gu + 1];

  unsigned* hw = (unsigned*)hs;

  // --- stage h0 into Ah (decoded); plain loads (prev kernel's data) ---
  {
    unsigned hv[8];
    if (h0src) {
      const unsigned* h0w = (const unsigned*)h0src + (size_t)(d * 513 + 512) * 4096 + tid * 8;
#pragma unroll
      for (int q = 0; q < 8; ++q) hv[q] = h0w[q];
    } else {
#pragma unroll
      for (int q = 0; q < 8; ++q) hv[q] = 0x80008000u;
    }
    unsigned* dst = (unsigned*)&Ah[tid >> 4][(tid & 15) * 16];
#pragma unroll
    for (int q = 0; q < 8; ++q) dst[q] = hv[q] ^ 0x80008000u;
  }

  // --- XG prefetch for step 0 ---
  u16 xgr[2][4];
  {
    int tin = d ? 0 : 511;
#pragma unroll
    for (int t = 0; t < 2; ++t) {
      int nt = 2 * p + t;
      int col = d * 1024 + (nt >> 1) * 256 + r * 32 + (nt & 1) * 16 + l15;
      const u16* xp = XG + (size_t)(tin * 32 + mt * 16 + quad * 4) * 2048 + col;
#pragma unroll
      for (int i = 0; i < 4; ++i) xgr[t][i] = xp[(size_t)i * 2048];
    }
  }

  for (int s = 0; s < 512; ++s) {
    __syncthreads();  // (B) Ah staged by all waves

    // matvec: g = h_s @ Wh_slice
    f32x4 acc0 = {0.f, 0.f, 0.f, 0.f}, acc1 = {0.f, 0.f, 0.f, 0.f};
#pragma unroll
    for (int kt = 0; kt < 8; ++kt) {
      bf16x8 ah = *(const bf16x8*)&Ah[mt * 16 + l15][kt * 32 + quad * 8];
      acc0 = __builtin_amdgcn_mfma_f32_16x16x32_bf16(ah, bfrag[0][kt].v, acc0, 0, 0, 0);
      acc1 = __builtin_amdgcn_mfma_f32_16x16x32_bf16(ah, bfrag[1][kt].v, acc1, 0, 0, 0);
    }

    // gate pre-activations -> gbuf[b][g*32 + lu]
#pragma unroll
    for (int i = 0; i < 4; ++i) {
      int bb = mt * 16 + quad * 4 + i;
      {
        int nt = 2 * p;
        gbuf[bb][(nt >> 1) * 32 + (nt & 1) * 16 + l15] = acc0[i] + bf2f(xgr[0][i]);
      }
      {
        int nt = 2 * p + 1;
        gbuf[bb][(nt >> 1) * 32 + (nt & 1) * 16 + l15] = acc1[i] + bf2f(xgr[1][i]);
      }
    }
    __syncthreads();  // (C) gbuf complete

    // gates (Keras i,f,c,o) for units lu0=2*j16, lu0+1
    {
      int lu = 2 * j16;
      float gi0 = gbuf[b_c][lu],      gi1 = gbuf[b_c][lu + 1];
      float gf0 = gbuf[b_c][32 + lu], gf1 = gbuf[b_c][32 + lu + 1];
      float gg0 = gbuf[b_c][64 + lu], gg1 = gbuf[b_c][64 + lu + 1];
      float go0 = gbuf[b_c][96 + lu], go1 = gbuf[b_c][96 + lu + 1];
      cv0 = sigf(gf0) * cv0 + sigf(gi0) * tanh_(gg0);
      cv1 = sigf(gf1) * cv1 + sigf(gi1) * tanh_(gg1);
      float h0f = sigf(go0) * tanh_(cv0);
      float h1f = sigf(go1) * tanh_(cv1);
      u16 e0 = f2bf(h0f); if (e0 == 0x8000u) e0 = 0;
      u16 e1 = f2bf(h1f); if (e1 == 0x8000u) e1 = 0;
      unsigned pk = ((unsigned)e0 | ((unsigned)e1 << 16)) ^ 0x80008000u;
      __hip_atomic_store(&hw[(size_t)(d * 513 + s + 1) * 4096 + b_c * 128 + r * 16 + j16],
                         pk, __ATOMIC_RELAXED, SCOPE_AGENT);
      if (s == 511) {
        c_dst[(d * 32 + b_c) * 256 + gu] = cv0;
        c_dst[(d * 32 + b_c) * 256 + gu + 1] = cv1;
      }
    }

    if (s < 511) {
      __syncthreads();  // (A) all waves published; Ah/gbuf safe to rewrite

      // prefetch XG for step s+1
      {
        int tin = d ? (s + 1) : (510 - s);
#pragma unroll
        for (int t = 0; t < 2; ++t) {
          int nt = 2 * p + t;
          int col = d * 1024 + (nt >> 1) * 256 + r * 32 + (nt & 1) * 16 + l15;
          const u16* xp = XG + (size_t)(tin * 32 + mt * 16 + quad * 4) * 2048 + col;
#pragma unroll
          for (int i = 0; i < 4; ++i) xgr[t][i] = xp[(size_t)i * 2048];
        }
      }

      // poll h_{s+1}: thread covers dwords tid*8 .. tid*8+7 (4 x u64)
      const unsigned long long* src =
          (const unsigned long long*)(hw + (size_t)(d * 513 + s + 1) * 4096) + tid * 4;
      unsigned long long w[4];
#pragma unroll
      for (int q2 = 0; q2 < 4; ++q2)
        w[q2] = __hip_atomic_load(src + q2, __ATOMIC_RELAXED, SCOPE_AGENT);
      for (;;) {
        bool all = true;
#pragma unroll
        for (int q2 = 0; q2 < 4; ++q2) {
          if ((unsigned)w[q2] == 0u || (unsigned)(w[q2] >> 32) == 0u) {
            all = false;
            w[q2] = __hip_atomic_load(src + q2, __ATOMIC_RELAXED, SCOPE_AGENT);
          }
        }
        if (all) break;
      }
      // stage decoded h into Ah
      unsigned* dst = (unsigned*)&Ah[tid >> 4][(tid & 15) * 16];
#pragma unroll
      for (int q2 = 0; q2 < 4; ++q2) {
        dst[q2 * 2]     = ((unsigned)w[q2]) ^ 0x80008000u;
        dst[q2 * 2 + 1] = ((unsigned)(w[q2] >> 32)) ^ 0x80008000u;
      }
    }
  }
}

// ---------------------------------------------------------------------------
// Next-layer GEMM input: A[t*32+b][u] = bf16( h_f[t+1] + h_b[512-t] ), decode.
__global__ __launch_bounds__(256) void k_mkA(const u16* __restrict__ hs, u16* __restrict__ A23) {
  int row = blockIdx.x;
  int t = row >> 5, b = row & 31, u = threadIdx.x;
  float vf = bf2f(hs[(size_t)(t + 1) * 8192 + b * 256 + u] ^ 0x8000u);
  float vb = bf2f(hs[(size_t)(513 + 512 - t) * 8192 + b * 256 + u] ^ 0x8000u);
  A23[(size_t)row * 256 + u] = f2bf(vf + vb);
}

// ---------------------------------------------------------------------------
__global__ __launch_bounds__(256) void k_epi(const u16* __restrict__ hs,
                                             const float* __restrict__ cC,
                                             const unsigned* __restrict__ flag,
                                             void* __restrict__ outv) {
  const int isf = (int)flag[0];
  float* outf = (float*)outv;
  u16* outb = (u16*)outv;
  int u = threadIdx.x;
  if (blockIdx.x < 16384) {  // out[b][s][u], blockIdx = b*512 + s
    int b = blockIdx.x >> 9, s = blockIdx.x & 511;
    float v = bf2f(hs[(size_t)(s + 1) * 8192 + b * 256 + u] ^ 0x8000u) +
              bf2f(hs[(size_t)(513 + 512 - s) * 8192 + b * 256 + u] ^ 0x8000u);
    size_t o = (size_t)blockIdx.x * 256 + u;
    if (isf) outf[o] = v; else outb[o] = f2bf(v);
  } else {  // final states: hf, cf, hb, cb
    int j = blockIdx.x - 16384;
    const size_t base = 16384ull * 256;
    float vhf = bf2f(hs[(size_t)512 * 8192 + j * 256 + u] ^ 0x8000u);
    float vcf = cC[j * 256 + u];
    float vhb = bf2f(hs[(size_t)1025 * 8192 + j * 256 + u] ^ 0x8000u);
    float vcb = cC[(32 + j) * 256 + u];
    size_t o0 = base + (size_t)j * 256 + u;
    if (isf) {
      outf[o0] = vhf; outf[o0 + 8192] = vcf; outf[o0 + 16384] = vhb; outf[o0 + 24576] = vcb;
    } else {
      outb[o0] = f2bf(vhf); outb[o0 + 8192] = f2bf(vcf);
      outb[o0 + 16384] = f2bf(vhb); outb[o0 + 24576] = f2bf(vcb);
    }
  }
}

// ---------------------------------------------------------------------------
extern "C" void kernel_launch(void* const* d_in, const int* in_sizes, int n_in,
                              void* d_out, int out_size, void* d_ws, size_t ws_size,
                              hipStream_t stream) {
  (void)in_sizes; (void)n_in; (void)out_size; (void)ws_size;
  const int* x   = (const int*)d_in[0];
  const void* emb = d_in[1];
  const void* Wi1f = d_in[2];  const void* Wh1f = d_in[3];  const void* b1f = d_in[4];
  const void* Wi1b = d_in[5];  const void* Wh1b = d_in[6];  const void* b1b = d_in[7];
  const void* Wi2f = d_in[8];  const void* Wh2f = d_in[9];  const void* b2f = d_in[10];
  const void* Wi2b = d_in[11]; const void* Wh2b = d_in[12]; const void* b2b = d_in[13];
  const void* Wi3f = d_in[14]; const void* Wh3f = d_in[15]; const void* b3f = d_in[16];
  const void* Wi3b = d_in[17]; const void* Wh3b = d_in[18]; const void* b3b = d_in[19];

  char* ws = (char*)d_ws;
  u16* X0   = (u16*)(ws + O_X0);
  u16* A23  = (u16*)(ws + O_X0);   // reuse: X0 dead after layer-1 GEMM
  u16* Wc1  = (u16*)(ws + O_WC1);
  u16* Wc2  = (u16*)(ws + O_WC2);
  u16* Wc3  = (u16*)(ws + O_WC3);
  u16* WhC  = (u16*)(ws + O_WH);
  float* bias = (float*)(ws + O_BIAS);
  unsigned* flag = (unsigned*)(ws + O_FLAG);
  float* c0 = (float*)(ws + O_C0);
  float* cA = (float*)(ws + O_CA);
  float* cB = (float*)(ws + O_CB);
  float* cC = (float*)(ws + O_CC);
  u16* hsA = (u16*)(ws + O_HSA);
  u16* hsB = (u16*)(ws + O_HSB);
  u16* XG  = (u16*)(ws + O_XG);

  k_detect<<<1, 64, 0, stream>>>((const unsigned*)emb, flag);
  k_prep<<<6144, 256, 0, stream>>>(Wi1f, Wi1b, Wi2f, Wi2b, Wi3f, Wi3b,
                                   Wh1f, Wh1b, Wh2f, Wh2b, Wh3f, Wh3b,
                                   b1f, b1b, b2f, b2b, b3f, b3b,
                                   flag, Wc1, Wc2, Wc3, WhC, bias, c0);
  k_zero<<<2048, 256, 0, stream>>>((uint4*)hsA, HS_U4);
  k_zero<<<2048, 256, 0, stream>>>((uint4*)hsB, HS_U4);
  k_embed<<<16384, 256, 0, stream>>>(x, emb, flag, X0);

  // layer 1
  k_gemm<<<2048, 256, 0, stream>>>(X0, Wc1, bias + 0, XG, 320);
  k_scan<<<16, 512, 0, stream>>>(XG, WhC + 0 * 262144, WhC + 1 * 262144, hsA, nullptr, c0, cA);
  // layer 2
  k_mkA<<<16384, 256, 0, stream>>>(hsA, A23);
  k_gemm<<<2048, 256, 0, stream>>>(A23, Wc2, bias + 2048, XG, 256);
  k_scan<<<16, 512, 0, stream>>>(XG, WhC + 2 * 262144, WhC + 3 * 262144, hsB, hsA, cA, cB);
  // hsA is dead (layer-2 scan consumed h0src at start); re-zero for layer 3
  k_zero<<<2048, 256, 0, stream>>>((uint4*)hsA, HS_U4);
  // layer 3
  k_mkA<<<16384, 256, 0, stream>>>(hsB, A23);
  k_gemm<<<2048, 256, 0, stream>>>(A23, Wc3, bias + 4096, XG, 256);
  k_scan<<<16, 512, 0, stream>>>(XG, WhC + 4 * 262144, WhC + 5 * 262144, hsA, hsB, cB, cC);

  k_epi<<<16416, 256, 0, stream>>>(hsA, cC, flag, d_out);
}